// Round 8
// baseline (321.102 us; speedup 1.0000x reference)
//
#include <hip/hip_runtime.h>
#include <hip/hip_bf16.h>

// ---------------------------------------------------------------------------
// SelfAttentionHybrid: single-head attention, B=4 S=2048 E=1024, fp32 in/out.
// R8: softmax fully absorbed with ZERO extra LDS/atomic work:
//   scores: P = exp(QK^T/32)            (exp-only epilogue)
//   PV:     O_unnorm = P.V, and rowsum via a synthetic all-ones B-tile
//           (rsum[row] = (P.1)[row]; no shuffles, no atomics, deterministic)
//   out:    y = (O.Wo^T)/rsum[row] + bo  (normalization commutes past Wo)
// QK-proj + V^T-proj merged into one dispatch. 5 dispatches total:
//   cast | proj(QK,VT) | scores | PV(+ones) | out
// GEMM core = R6 (32x32x16 MFMA, XOR swizzle, global_load_lds w16, L2
// supertile remap). 4cy/ds_read_b128 conflict tax accepted as intrinsic.
// ---------------------------------------------------------------------------

typedef __bf16 bf16_t;
typedef __bf16 bf16x8 __attribute__((ext_vector_type(8)));
typedef __bf16 bf16x4 __attribute__((ext_vector_type(4)));
typedef float  f32x16 __attribute__((ext_vector_type(16)));

__device__ __forceinline__ void async_copy16(const void* g, void* l) {
  __builtin_amdgcn_global_load_lds(
      (const __attribute__((address_space(1))) void*)g,
      (__attribute__((address_space(3))) void*)l, 16, 0, 0);
}

__device__ __forceinline__ void store_out(float* p, float v)  { *p = v; }
__device__ __forceinline__ void store_out(bf16_t* p, float v) { *p = (bf16_t)v; }

#define BM 128
#define BN 128
#define BKT 64

// L2 supertile remap: 8 y-tiles per supertile, y-fastest inside.
__device__ __forceinline__ void supertile(int id, int GX, int& bx, int& by) {
  const int per = GX * 8;
  const int grp = id / per;
  const int rem = id - grp * per;
  by = grp * 8 + (rem & 7);
  bx = rem >> 3;
}

// ---------------------------------------------------------------------------
// Core: C[M,N] tile = A[.,K](lda) x B[.,K](ldb)^T, bf16 in, fp32 acc.
// BIAS: 0 none | 1 col b0 | 2 col split b0/b1 | 3 row b0    (EPI==0 only)
// EPI:  0 scale+bias | 1 exp(scale*acc) | 3 acc/rsum[row] + b0[col]
//       4 (with ONES) write rsum[row] only
// ONES: B never staged; Bs pre-filled with 1.0 -> acc = row sums of A.
// ---------------------------------------------------------------------------
template <typename OutT, int BIAS, int EPI, bool ONES>
__device__ __forceinline__ void gemm_core(
    const bf16_t* __restrict__ A, const bf16_t* __restrict__ B,
    OutT* __restrict__ C, const float* __restrict__ b0,
    const float* __restrict__ b1, float* __restrict__ rsum,
    int K, int lda, int ldb, int ldc, float scale,
    int tileM, int tileN, bf16_t* As, bf16_t* Bs) {
  const int t    = threadIdx.x;
  const int lane = t & 63;
  const int w    = t >> 6;
  const int wm   = w & 1;
  const int wn   = w >> 1;

  if (ONES) {
    bf16x8 ones8;
#pragma unroll
    for (int j = 0; j < 8; ++j) ones8[j] = (bf16_t)1.0f;
    for (int i = t; i < BN * BKT / 8; i += 256) ((bf16x8*)Bs)[i] = ones8;
  }

  f32x16 acc[2][2] = {};

  for (int k0 = 0; k0 < K; k0 += BKT) {
#pragma unroll
    for (int i = 0; i < 4; ++i) {
      const int c   = t + 256 * i;
      const int row = c >> 3;
      const int cc  = c & 7;
      const int gcc = cc ^ (row & 7);
      const int ldsbase = ((t & ~63) + 256 * i) * 8;  // wave-uniform base
      async_copy16(A + (long long)(tileM + row) * lda + k0 + gcc * 8, &As[ldsbase]);
      if (!ONES)
        async_copy16(B + (long long)(tileN + row) * ldb + k0 + gcc * 8, &Bs[ldsbase]);
    }
    __syncthreads();

#pragma unroll
    for (int s = 0; s < 4; ++s) {        // step s consumes chunks {s, s+4}
      const int kc = s + 4 * (lane >> 5);
      bf16x8 af[2], bfr[2];
#pragma unroll
      for (int ti = 0; ti < 2; ++ti) {
        const int row = wm * 64 + ti * 32 + (lane & 31);
        af[ti] = *(const bf16x8*)&As[row * BKT + ((kc ^ (row & 7)) * 8)];
      }
#pragma unroll
      for (int tj = 0; tj < 2; ++tj) {
        const int row = wn * 64 + tj * 32 + (lane & 31);
        bfr[tj] = *(const bf16x8*)&Bs[row * BKT + ((kc ^ (row & 7)) * 8)];
      }
#pragma unroll
      for (int ti = 0; ti < 2; ++ti)
#pragma unroll
        for (int tj = 0; tj < 2; ++tj)
          acc[ti][tj] = __builtin_amdgcn_mfma_f32_32x32x16_bf16(
              af[ti], bfr[tj], acc[ti][tj], 0, 0, 0);
    }
    __syncthreads();
  }

  // ---- epilogues. C map: col = lane&31 (+tj*32+wn*64),
  //                        row = (r&3)+8*(r>>2)+4*(lane>>5) (+ti*32+wm*64)
  if (EPI == 4) {
    // ones tile: every col holds the row sum; one lane per row stores it
    if (wn == 0 && (lane & 31) == 0) {
#pragma unroll
      for (int ti = 0; ti < 2; ++ti) {
        const int rowb = tileM + wm * 64 + ti * 32 + 4 * (lane >> 5);
#pragma unroll
        for (int r = 0; r < 16; ++r)
          rsum[rowb + (r & 3) + 8 * (r >> 2)] = acc[ti][0][r];
      }
    }
  } else if (EPI == 1) {
    const int col0 = tileN + wn * 64 + (lane & 31);
#pragma unroll
    for (int ti = 0; ti < 2; ++ti) {
      const int rowb = tileM + wm * 64 + ti * 32 + 4 * (lane >> 5);
#pragma unroll
      for (int r = 0; r < 16; ++r) {
        const int row = rowb + (r & 3) + 8 * (r >> 2);
        store_out(&C[(long long)row * ldc + col0],      __expf(acc[ti][0][r] * scale));
        store_out(&C[(long long)row * ldc + col0 + 32], __expf(acc[ti][1][r] * scale));
      }
    }
  } else if (EPI == 3) {
    const int col0 = tileN + wn * 64 + (lane & 31);
    const float bv0 = b0[col0], bv1 = b0[col0 + 32];
#pragma unroll
    for (int ti = 0; ti < 2; ++ti) {
      const int rowb = tileM + wm * 64 + ti * 32 + 4 * (lane >> 5);
#pragma unroll
      for (int r = 0; r < 16; ++r) {
        const int row = rowb + (r & 3) + 8 * (r >> 2);
        const float inv = 1.0f / rsum[row];
        store_out(&C[(long long)row * ldc + col0],      acc[ti][0][r] * inv + bv0);
        store_out(&C[(long long)row * ldc + col0 + 32], acc[ti][1][r] * inv + bv1);
      }
    }
  } else if (BIAS == 3) {
    const int col0 = tileN + wn * 64 + (lane & 31);
#pragma unroll
    for (int ti = 0; ti < 2; ++ti) {
      const int rowb = tileM + wm * 64 + ti * 32 + 4 * (lane >> 5);
#pragma unroll
      for (int r = 0; r < 16; ++r) {
        const int row = rowb + (r & 3) + 8 * (r >> 2);
        const float bv = b0[row];
        store_out(&C[(long long)row * ldc + col0],      acc[ti][0][r] * scale + bv);
        store_out(&C[(long long)row * ldc + col0 + 32], acc[ti][1][r] * scale + bv);
      }
    }
  } else {
#pragma unroll
    for (int tj = 0; tj < 2; ++tj) {
      const int col = tileN + wn * 64 + tj * 32 + (lane & 31);
      float bv = 0.f;
      if (BIAS == 1) bv = b0[col];
      if (BIAS == 2) bv = (col < 1024 ? b0[col] : b1[col - 1024]);
#pragma unroll
      for (int ti = 0; ti < 2; ++ti) {
        const int rowb = tileM + wm * 64 + ti * 32 + 4 * (lane >> 5);
#pragma unroll
        for (int r = 0; r < 16; ++r) {
          const int row = rowb + (r & 3) + 8 * (r >> 2);
          store_out(&C[(long long)row * ldc + col], acc[ti][tj][r] * scale + bv);
        }
      }
    }
  }
}

#define LDS_DECL \
  __shared__ __align__(16) bf16_t As[BM * BKT]; \
  __shared__ __align__(16) bf16_t Bs[BN * BKT];

// ---- merged projections: blocks [0,1024) QK, [1024,1536) V^T --------------
__global__ __launch_bounds__(256) void proj_kernel(
    const bf16_t* __restrict__ xb, const bf16_t* __restrict__ Wqkb,
    const bf16_t* __restrict__ Wvb, bf16_t* __restrict__ QKb,
    bf16_t* __restrict__ VTb, const float* __restrict__ bq,
    const float* __restrict__ bk, const float* __restrict__ bv) {
  LDS_DECL;
  const int id = blockIdx.x;
  if (id < 1024) {  // QK: [8192,2048] = xb . Wqk^T + (bq|bk)
    int bx, by; supertile(id, 16, bx, by);
    gemm_core<bf16_t, 2, 0, false>(xb, Wqkb, QKb, bq, bk, nullptr,
        1024, 1024, 1024, 2048, 1.f, by * 128, bx * 128, As, Bs);
  } else {          // V^T: [1024,8192] = Wv . xb^T + bv(row)
    int bx, by; supertile(id - 1024, 64, bx, by);
    gemm_core<bf16_t, 3, 0, false>(Wvb, xb, VTb, bv, nullptr, nullptr,
        1024, 1024, 1024, 8192, 1.f, by * 128, bx * 128, As, Bs);
  }
}

// ---- scores: P = exp(Q.K^T / 32), per batch -------------------------------
__global__ __launch_bounds__(256) void scores_kernel(
    const bf16_t* __restrict__ QKb, bf16_t* __restrict__ Sb) {
  LDS_DECL;
  const int z = blockIdx.z;
  const bf16_t* A = QKb + (long long)z * 2048 * 2048;
  const bf16_t* Bm = A + 1024;
  bf16_t* C = Sb + (long long)z * 2048 * 2048;
  int bx, by; supertile(blockIdx.y * 16 + blockIdx.x, 16, bx, by);
  gemm_core<bf16_t, 0, 1, false>(A, Bm, C, nullptr, nullptr, nullptr,
      1024, 2048, 2048, 2048, 0.03125f, by * 128, bx * 128, As, Bs);
}

// ---- PV: O_unnorm = P.V (normal tiles) + rowsum (ones tile) ---------------
__global__ __launch_bounds__(256) void pv_kernel(
    const bf16_t* __restrict__ Sb, const bf16_t* __restrict__ VTb,
    bf16_t* __restrict__ Ob, float* __restrict__ rsum) {
  LDS_DECL;
  const int z = blockIdx.z;
  const bf16_t* A = Sb + (long long)z * 2048 * 2048;
  const bf16_t* Bm = VTb + (long long)z * 2048;  // col offset into [1024,8192]
  bf16_t* C = Ob + (long long)z * 2048 * 1024;
  float* rs = rsum + z * 2048;
  if (blockIdx.x == 8) {  // ones tile -> row sums
    gemm_core<bf16_t, 0, 4, true>(A, nullptr, C, nullptr, nullptr, rs,
        2048, 2048, 0, 1024, 1.f, blockIdx.y * 128, 0, As, Bs);
  } else {
    int bx, by; supertile(blockIdx.y * 8 + blockIdx.x, 8, bx, by);
    gemm_core<bf16_t, 0, 0, false>(A, Bm, C, nullptr, nullptr, nullptr,
        2048, 2048, 8192, 1024, 1.f, by * 128, bx * 128, As, Bs);
  }
}

// ---- out-proj: y = (O.Wo^T)/rsum[row] + bo --------------------------------
__global__ __launch_bounds__(256) void out_kernel(
    const bf16_t* __restrict__ Ob, const bf16_t* __restrict__ Wob,
    float* __restrict__ out, const float* __restrict__ bo,
    const float* __restrict__ rsum) {
  LDS_DECL;
  int bx, by; supertile(blockIdx.y * 8 + blockIdx.x, 8, bx, by);
  gemm_core<float, 1, 3, false>(Ob, Wob, out, bo, nullptr,
      const_cast<float*>(rsum),
      1024, 1024, 1024, 1024, 1.f, by * 128, bx * 128, As, Bs);
}

// ---- fused cast: 4 weights + x, one dispatch ------------------------------
__global__ __launch_bounds__(256) void cast_all(
    const float4* __restrict__ w0, const float4* __restrict__ w1,
    const float4* __restrict__ w2, const float4* __restrict__ w3,
    const float4* __restrict__ x,
    bf16x4* __restrict__ wdst, bf16x4* __restrict__ xdst) {
  const int N4W = 1 << 18;  // per-weight float4 count
  const int id = blockIdx.x * 256 + threadIdx.x;
  const float4* src;
  bf16x4* dst;
  if (id < 4 * N4W) {
    const int zz = id >> 18;
    src = (zz == 0 ? w0 : zz == 1 ? w1 : zz == 2 ? w2 : w3) + (id & (N4W - 1));
    dst = wdst + id;
  } else {
    const int i = id - 4 * N4W;
    src = x + i;
    dst = xdst + i;
  }
  const float4 v = *src;
  bf16x4 o;
  o[0] = (bf16_t)v.x; o[1] = (bf16_t)v.y; o[2] = (bf16_t)v.z; o[3] = (bf16_t)v.w;
  *dst = o;
}

// ---------------------------------------------------------------------------
extern "C" void kernel_launch(void* const* d_in, const int* in_sizes, int n_in,
                              void* d_out, int out_size, void* d_ws, size_t ws_size,
                              hipStream_t stream) {
  const int E = 1024, S = 2048, B = 4;
  const int BS = B * S;  // 8192

  const float* x  = (const float*)d_in[0];
  const float* Wq = (const float*)d_in[1];
  const float* bq = (const float*)d_in[2];
  const float* Wk = (const float*)d_in[3];
  const float* bk = (const float*)d_in[4];
  const float* Wv = (const float*)d_in[5];
  const float* bv = (const float*)d_in[6];
  const float* Wo = (const float*)d_in[7];
  const float* bo = (const float*)d_in[8];
  float* out = (float*)d_out;

  char* w = (char*)d_ws;
  const size_t MB = 1ull << 20;
  bf16_t* Wqkb = (bf16_t*)(w + 0 * MB);    // 8 MB: Wq|Wk|Wv|Wo bf16
  bf16_t* Wvb  = Wqkb + 2 * E * E;
  bf16_t* Wob  = Wqkb + 3 * E * E;
  bf16_t* xb   = (bf16_t*)(w + 8 * MB);    // 16 MB [8192,1024]
  bf16_t* Ob   = (bf16_t*)(w + 8 * MB);    // overlays xb (dead after proj)
  bf16_t* QKb  = (bf16_t*)(w + 24 * MB);   // 32 MB [8192,2048] = Q|K
  bf16_t* VTb  = (bf16_t*)(w + 56 * MB);   // 16 MB [1024,8192] = V^T
  bf16_t* Sb   = (bf16_t*)(w + 72 * MB);   // 32 MB [B][2048,2048] = exp(scores)
  float*  rsum = (float*)(w + 104 * MB);   // 32 KB [8192]

  // 1. casts
  cast_all<<<((4 << 18) + (1 << 21)) / 256, 256, 0, stream>>>(
      (const float4*)Wq, (const float4*)Wk, (const float4*)Wv,
      (const float4*)Wo, (const float4*)x, (bf16x4*)Wqkb, (bf16x4*)xb);

  // 2. projections (QK + V^T in one dispatch)
  proj_kernel<<<1536, 256, 0, stream>>>(xb, Wqkb, Wvb, QKb, VTb, bq, bk, bv);

  // 3. scores: P = exp(QK^T/32)
  scores_kernel<<<dim3(16, 16, B), 256, 0, stream>>>(QKb, Sb);

  // 4. PV: O_unnorm + rowsum (ones tile at x==8)
  pv_kernel<<<dim3(9, 16, B), 256, 0, stream>>>(Sb, VTb, Ob, rsum);

  // 5. out-proj with fused normalization + bias
  out_kernel<<<dim3(8, BS / BM, 1), 256, 0, stream>>>(Ob, Wob, out, bo, rsum);
}